// Round 5
// baseline (173.087 us; speedup 1.0000x reference)
//
#include <hip/hip_runtime.h>

// Problem constants: B=4, L=2048, C=64, D=4
#define BB 4
#define LL 2048
#define CC 64
#define DD 4
#define NN (CC * DD * DD)   // 1024 chains per batch
#define AN (CC * DD)        // 256 A-entries per timestep per batch (c*4+i)
#define TPB 256             // threads per block = time segments per chain
#define TT (LL / TPB)       // 8 timesteps per thread

typedef float f32x4 __attribute__((ext_vector_type(4)));

// ---------------------------------------------------------------------------
// Single-pass kernel. Block = one (b, n4): the 4 chains j=0..3 sharing one A
// value, over the FULL length L. Thread tid owns timesteps [tid*8, tid*8+8).
// A,X live in registers across the whole kernel; the chunk-carry scan is a
// block-internal LDS Hillis-Steele scan (no grid sync, no extra passes).
// HBM traffic: read A+X once (84 MB) + write out once (67 MB).
//
// Lanes are time-adjacent, so each 16 B lane-load touches its own 64 B line;
// the remaining 48 B belong to the 3 adjacent-n4 blocks. The chunked XCD
// swizzle places adjacent-n4 blocks on the SAME XCD so its L2 fetches each
// line once.
// ---------------------------------------------------------------------------
__global__ __launch_bounds__(256) void pscan_onepass(
    const float* __restrict__ A_re, const float* __restrict__ A_im,
    const f32x4* __restrict__ X_re4, const f32x4* __restrict__ X_im4,
    f32x4* __restrict__ out4) {
  // HW round-robins consecutive blockIdx across 8 XCDs; remap so each XCD
  // owns a contiguous sid range (bijective on [0,1024)).
  const int sid = (blockIdx.x & 7) * 128 + (blockIdx.x >> 3);
  const int n4  = sid & (AN - 1);
  const int b   = sid >> 8;
  const int tid = threadIdx.x;
  const int t0  = tid * TT;
  const int base = (b * LL + t0) * AN + n4;   // index for A (float) and X (f32x4)

  // ---- load this thread's A and X slices into registers ----
  float ar[TT], ai[TT];
  f32x4 xr[TT], xi[TT];
#pragma unroll
  for (int t = 0; t < TT; ++t) {
    ar[t] = A_re[base + t * AN];
    ai[t] = A_im[base + t * AN];
    xr[t] = X_re4[base + t * AN];
    xi[t] = X_im4[base + t * AN];
  }

  // ---- local segment aggregate (p = prod A, s_j = zero-seeded scan) ----
  float p_re = 1.f, p_im = 0.f;
  float s_re[4] = {0.f, 0.f, 0.f, 0.f};
  float s_im[4] = {0.f, 0.f, 0.f, 0.f};
#pragma unroll
  for (int t = 0; t < TT; ++t) {
    const float are = ar[t], aim = ai[t];
    const float npre = are * p_re - aim * p_im;
    const float npim = are * p_im + aim * p_re;
    p_re = npre; p_im = npim;
#pragma unroll
    for (int j = 0; j < 4; ++j) {
      const float nsre = are * s_re[j] - aim * s_im[j] + xr[t][j];
      const float nsim = are * s_im[j] + aim * s_re[j] + xi[t][j];
      s_re[j] = nsre; s_im[j] = nsim;
    }
  }

  // ---- block-level inclusive Hillis-Steele scan over 256 segment tuples ----
  // tuple = (p_re, p_im, s_re[0..3], s_im[0..3]); row stride 11 floats (odd)
  // so the bank stride is coprime with 32 -> conflict-free.
  __shared__ float lds[TPB][11];
  lds[tid][0] = p_re; lds[tid][1] = p_im;
#pragma unroll
  for (int j = 0; j < 4; ++j) { lds[tid][2 + j] = s_re[j]; lds[tid][6 + j] = s_im[j]; }

  float vp_re = p_re, vp_im = p_im;
  float vs_re[4], vs_im[4];
#pragma unroll
  for (int j = 0; j < 4; ++j) { vs_re[j] = s_re[j]; vs_im[j] = s_im[j]; }

  for (int d = 1; d < TPB; d <<= 1) {
    __syncthreads();
    float wp_re = 1.f, wp_im = 0.f;
    float ws_re[4] = {0.f, 0.f, 0.f, 0.f};
    float ws_im[4] = {0.f, 0.f, 0.f, 0.f};
    if (tid >= d) {
      wp_re = lds[tid - d][0]; wp_im = lds[tid - d][1];
#pragma unroll
      for (int j = 0; j < 4; ++j) { ws_re[j] = lds[tid - d][2 + j]; ws_im[j] = lds[tid - d][6 + j]; }
    }
    __syncthreads();
    if (tid >= d) {
      // combine(earlier = w, later = v): p' = vp*wp ; s' = vp*ws + vs
      const float np_re = vp_re * wp_re - vp_im * wp_im;
      const float np_im = vp_re * wp_im + vp_im * wp_re;
#pragma unroll
      for (int j = 0; j < 4; ++j) {
        const float ns_re = vp_re * ws_re[j] - vp_im * ws_im[j] + vs_re[j];
        const float ns_im = vp_re * ws_im[j] + vp_im * ws_re[j] + vs_im[j];
        vs_re[j] = ns_re; vs_im[j] = ns_im;
      }
      vp_re = np_re; vp_im = np_im;
      lds[tid][0] = vp_re; lds[tid][1] = vp_im;
#pragma unroll
      for (int j = 0; j < 4; ++j) { lds[tid][2 + j] = vs_re[j]; lds[tid][6 + j] = vs_im[j]; }
    }
  }
  __syncthreads();

  // ---- exclusive carry = inclusive value of tid-1 (identity for tid 0) ----
  float y_re[4] = {0.f, 0.f, 0.f, 0.f};
  float y_im[4] = {0.f, 0.f, 0.f, 0.f};
  if (tid > 0) {
#pragma unroll
    for (int j = 0; j < 4; ++j) { y_re[j] = lds[tid - 1][2 + j]; y_im[j] = lds[tid - 1][6 + j]; }
  }

  // ---- re-run recurrence from registers, store out ----
  const int ob = (b * LL + t0) * (2 * AN) + n4 * 2;   // f32x4 index into out
#pragma unroll
  for (int t = 0; t < TT; ++t) {
    const float are = ar[t], aim = ai[t];
#pragma unroll
    for (int j = 0; j < 4; ++j) {
      const float ny_re = are * y_re[j] - aim * y_im[j] + xr[t][j];
      const float ny_im = are * y_im[j] + aim * y_re[j] + xi[t][j];
      y_re[j] = ny_re; y_im[j] = ny_im;
    }
    f32x4 o0 = {y_re[0], y_im[0], y_re[1], y_im[1]};
    f32x4 o1 = {y_re[2], y_im[2], y_re[3], y_im[3]};
    out4[ob + t * (2 * AN)]     = o0;
    out4[ob + t * (2 * AN) + 1] = o1;
  }
}

extern "C" void kernel_launch(void* const* d_in, const int* in_sizes, int n_in,
                              void* d_out, int out_size, void* d_ws, size_t ws_size,
                              hipStream_t stream) {
  const float* A_re  = (const float*)d_in[0];
  const float* A_im  = (const float*)d_in[1];
  const f32x4* X_re4 = (const f32x4*)d_in[2];
  const f32x4* X_im4 = (const f32x4*)d_in[3];
  f32x4* out4 = (f32x4*)d_out;
  (void)d_ws; (void)ws_size;  // no workspace needed

  const int blocks = BB * AN;   // 1024 blocks: one per (b, n4)
  pscan_onepass<<<blocks, TPB, 0, stream>>>(A_re, A_im, X_re4, X_im4, out4);
}

// Round 6
// 167.911 us; speedup vs baseline: 1.0308x; 1.0308x over previous
//
#include <hip/hip_runtime.h>

// Problem constants: B=4, L=2048, C=64, D=4
#define BB 4
#define LL 2048
#define CC 64
#define DD 4
#define NN (CC * DD * DD)   // 1024 chains per batch
#define AN (CC * DD)        // 256 A-entries per timestep per batch (c*4+i)
#define TPB 512             // threads per block
#define N4PB 4              // n4 values per block
#define NSEGS (TPB / N4PB)  // 128 time segments per chain
#define TT (LL / NSEGS)     // 16 timesteps per thread

typedef float f32x4 __attribute__((ext_vector_type(4)));

// ---------------------------------------------------------------------------
// One-dispatch pscan, v2. Block = (b, group of 4 consecutive n4) over full L.
// Thread tid: n4l = tid&3 (which n4), tseg = tid>>2 (which 16-step segment).
// A quad of adjacent lanes (same tseg, n4l=0..3) reads 4 consecutive f32x4 of
// X = one full 64 B line per load -> 4x fewer line-requests than v1 (v1 was
// transaction-bound: 1.4 TB/s, 64 lines/wave-load, 23% occupancy).
// Pass 1 streams A+X computing per-segment aggregates (A kept in 32 VGPRs);
// 7-round LDS Hillis-Steele scan (4 independent n4 groups of 128 segments);
// pass 2 re-reads X (L2/L3-resident, coalesced) and stores y coalesced.
// HBM traffic: read A+X once (80 MB) + write out once (64 MB).
// ---------------------------------------------------------------------------
__global__ __launch_bounds__(512) void pscan_onepass2(
    const float* __restrict__ A_re, const float* __restrict__ A_im,
    const f32x4* __restrict__ X_re4, const f32x4* __restrict__ X_im4,
    f32x4* __restrict__ out4) {
  const int b    = blockIdx.x >> 6;          // [0,4)
  const int n4g  = blockIdx.x & 63;          // [0,64)
  const int tid  = threadIdx.x;
  const int n4l  = tid & (N4PB - 1);
  const int tseg = tid >> 2;                 // [0,128)
  const int n4   = n4g * N4PB + n4l;
  const int t0   = tseg * TT;
  const int base = (b * LL + t0) * AN + n4;  // index for A (float) and X (f32x4)

  // ---- pass 1: stream A,X; retain A; compute segment aggregate ----
  float ar[TT], ai[TT];
  float p_re = 1.f, p_im = 0.f;
  float s_re[4] = {0.f, 0.f, 0.f, 0.f};
  float s_im[4] = {0.f, 0.f, 0.f, 0.f};
#pragma unroll
  for (int t = 0; t < TT; ++t) {
    const float are = A_re[base + t * AN];
    const float aim = A_im[base + t * AN];
    ar[t] = are; ai[t] = aim;
    const f32x4 xr = X_re4[base + t * AN];
    const f32x4 xi = X_im4[base + t * AN];
    const float npre = are * p_re - aim * p_im;
    const float npim = are * p_im + aim * p_re;
    p_re = npre; p_im = npim;
#pragma unroll
    for (int j = 0; j < 4; ++j) {
      const float nsre = are * s_re[j] - aim * s_im[j] + xr[j];
      const float nsim = are * s_im[j] + aim * s_re[j] + xi[j];
      s_re[j] = nsre; s_im[j] = nsim;
    }
  }

  // ---- block-level inclusive Hillis-Steele scan (per n4 group) ----
  // tuple q = tseg*4 + n4l, 11-float stride: quad lanes -> banks {0,11,22,1}
  // (conflict-free); (t,t+8) same-bank pairs are 2-way = free on CDNA4.
  __shared__ float lds[TPB * 11];
  const int q = tid * 11;                    // == (tseg*4 + n4l) * 11
  lds[q + 0] = p_re; lds[q + 1] = p_im;
#pragma unroll
  for (int j = 0; j < 4; ++j) { lds[q + 2 + j] = s_re[j]; lds[q + 6 + j] = s_im[j]; }

  float vp_re = p_re, vp_im = p_im;
  float vs_re[4], vs_im[4];
#pragma unroll
  for (int j = 0; j < 4; ++j) { vs_re[j] = s_re[j]; vs_im[j] = s_im[j]; }

  for (int d = 1; d < NSEGS; d <<= 1) {
    __syncthreads();
    float wp_re = 1.f, wp_im = 0.f;
    float ws_re[4] = {0.f, 0.f, 0.f, 0.f};
    float ws_im[4] = {0.f, 0.f, 0.f, 0.f};
    if (tseg >= d) {
      const int q2 = q - d * (N4PB * 11);    // (tseg-d)*4 + n4l, same n4 group
      wp_re = lds[q2 + 0]; wp_im = lds[q2 + 1];
#pragma unroll
      for (int j = 0; j < 4; ++j) { ws_re[j] = lds[q2 + 2 + j]; ws_im[j] = lds[q2 + 6 + j]; }
    }
    __syncthreads();
    if (tseg >= d) {
      // combine(earlier = w, later = v): p' = vp*wp ; s' = vp*ws + vs
      const float np_re = vp_re * wp_re - vp_im * wp_im;
      const float np_im = vp_re * wp_im + vp_im * wp_re;
#pragma unroll
      for (int j = 0; j < 4; ++j) {
        const float ns_re = vp_re * ws_re[j] - vp_im * ws_im[j] + vs_re[j];
        const float ns_im = vp_re * ws_im[j] + vp_im * ws_re[j] + vs_im[j];
        vs_re[j] = ns_re; vs_im[j] = ns_im;
      }
      vp_re = np_re; vp_im = np_im;
      lds[q + 0] = vp_re; lds[q + 1] = vp_im;
#pragma unroll
      for (int j = 0; j < 4; ++j) { lds[q + 2 + j] = vs_re[j]; lds[q + 6 + j] = vs_im[j]; }
    }
  }
  __syncthreads();

  // ---- exclusive carry = inclusive value of segment tseg-1 (same n4) ----
  float y_re[4] = {0.f, 0.f, 0.f, 0.f};
  float y_im[4] = {0.f, 0.f, 0.f, 0.f};
  if (tseg > 0) {
    const int qc = q - N4PB * 11;
#pragma unroll
    for (int j = 0; j < 4; ++j) { y_re[j] = lds[qc + 2 + j]; y_im[j] = lds[qc + 6 + j]; }
  }

  // ---- pass 2: re-read X (L2/L3-warm, coalesced), apply, store ----
  const int ob = (b * LL + t0) * (2 * AN) + n4 * 2;  // f32x4 index into out
#pragma unroll
  for (int t = 0; t < TT; ++t) {
    const float are = ar[t], aim = ai[t];
    const f32x4 xr = X_re4[base + t * AN];
    const f32x4 xi = X_im4[base + t * AN];
#pragma unroll
    for (int j = 0; j < 4; ++j) {
      const float ny_re = are * y_re[j] - aim * y_im[j] + xr[j];
      const float ny_im = are * y_im[j] + aim * y_re[j] + xi[j];
      y_re[j] = ny_re; y_im[j] = ny_im;
    }
    f32x4 o0 = {y_re[0], y_im[0], y_re[1], y_im[1]};
    f32x4 o1 = {y_re[2], y_im[2], y_re[3], y_im[3]};
    out4[ob + t * (2 * AN)]     = o0;
    out4[ob + t * (2 * AN) + 1] = o1;
  }
}

extern "C" void kernel_launch(void* const* d_in, const int* in_sizes, int n_in,
                              void* d_out, int out_size, void* d_ws, size_t ws_size,
                              hipStream_t stream) {
  const float* A_re  = (const float*)d_in[0];
  const float* A_im  = (const float*)d_in[1];
  const f32x4* X_re4 = (const f32x4*)d_in[2];
  const f32x4* X_im4 = (const f32x4*)d_in[3];
  f32x4* out4 = (f32x4*)d_out;
  (void)d_ws; (void)ws_size;  // no workspace needed

  const int blocks = BB * (AN / N4PB);   // 256 blocks: one per (b, 4-n4 group)
  pscan_onepass2<<<blocks, TPB, 0, stream>>>(A_re, A_im, X_re4, X_im4, out4);
}

// Round 7
// 142.164 us; speedup vs baseline: 1.2175x; 1.1811x over previous
//
#include <hip/hip_runtime.h>

// Problem constants: B=4, L=2048, C=64, D=4
#define BB 4
#define LL 2048
#define CC 64
#define DD 4
#define NN (CC * DD * DD)   // 1024 chains per batch
#define AN (CC * DD)        // 256 A-entries per timestep per batch (c*4+i)
#define TPB 512             // threads per block
#define N4PB 4              // n4 values per block
#define NSEGS (TPB / N4PB)  // 128 time segments per chain
#define TT (LL / NSEGS)     // 16 timesteps per thread

typedef float f32x4 __attribute__((ext_vector_type(4)));

// ---------------------------------------------------------------------------
// One-dispatch pscan, v3. Block = (b, group of 4 consecutive n4) over full L.
// Thread tid: n4l = tid&3, tseg = tid>>2. Quad lanes read one full 64 B line
// of X per load (v2's fix, kept). New in v3:
//  - X is held in VGPRs across the block scan -> NO second pass over X
//    (v2's pass-2 re-read missed L2 and cost 64 MB of HBM: FETCH was 196 MB).
//  - chunked XCD swizzle: the 4 consecutive blocks sharing each 64 B A-line
//    land on the same XCD's L2 (v2 round-robined them across 4 XCDs, 4x A).
// HBM traffic: read A+X once (80 MB) + write out once (64 MB).
// ~200 VGPR -> 2 waves/SIMD (launch_bounds(512,2)); 256 blocks = 1 block/CU.
// ---------------------------------------------------------------------------
__global__ __launch_bounds__(512, 2) void pscan_onepass3(
    const float* __restrict__ A_re, const float* __restrict__ A_im,
    const f32x4* __restrict__ X_re4, const f32x4* __restrict__ X_im4,
    f32x4* __restrict__ out4) {
  // HW round-robins consecutive blockIdx across 8 XCDs; remap so XCD k owns
  // the contiguous sid range [32k, 32k+32) (bijective on [0,256)).
  const int sid = (blockIdx.x & 7) * 32 + (blockIdx.x >> 3);
  const int b    = sid >> 6;                 // [0,4)
  const int n4g  = sid & 63;                 // [0,64)
  const int tid  = threadIdx.x;
  const int n4l  = tid & (N4PB - 1);
  const int tseg = tid >> 2;                 // [0,128)
  const int n4   = n4g * N4PB + n4l;
  const int t0   = tseg * TT;
  const int base = (b * LL + t0) * AN + n4;  // index for A (float) and X (f32x4)

  // ---- pass 1: load A,X into registers; compute segment aggregate ----
  float ar[TT], ai[TT];
  f32x4 xr[TT], xi[TT];
  float p_re = 1.f, p_im = 0.f;
  float s_re[4] = {0.f, 0.f, 0.f, 0.f};
  float s_im[4] = {0.f, 0.f, 0.f, 0.f};
#pragma unroll
  for (int t = 0; t < TT; ++t) {
    const float are = A_re[base + t * AN];
    const float aim = A_im[base + t * AN];
    ar[t] = are; ai[t] = aim;
    xr[t] = X_re4[base + t * AN];
    xi[t] = X_im4[base + t * AN];
    const float npre = are * p_re - aim * p_im;
    const float npim = are * p_im + aim * p_re;
    p_re = npre; p_im = npim;
#pragma unroll
    for (int j = 0; j < 4; ++j) {
      const float nsre = are * s_re[j] - aim * s_im[j] + xr[t][j];
      const float nsim = are * s_im[j] + aim * s_re[j] + xi[t][j];
      s_re[j] = nsre; s_im[j] = nsim;
    }
  }

  // ---- block-level inclusive Hillis-Steele scan (per n4 group) ----
  // tuple q = tid, 11-float stride: quad lanes -> banks {0,11,22,1} etc.
  // (conflict-free); worst aliasing 2-way = free on CDNA4.
  __shared__ float lds[TPB * 11];
  const int q = tid * 11;
  lds[q + 0] = p_re; lds[q + 1] = p_im;
#pragma unroll
  for (int j = 0; j < 4; ++j) { lds[q + 2 + j] = s_re[j]; lds[q + 6 + j] = s_im[j]; }

  float vp_re = p_re, vp_im = p_im;
  float vs_re[4], vs_im[4];
#pragma unroll
  for (int j = 0; j < 4; ++j) { vs_re[j] = s_re[j]; vs_im[j] = s_im[j]; }

  for (int d = 1; d < NSEGS; d <<= 1) {
    __syncthreads();
    float wp_re = 1.f, wp_im = 0.f;
    float ws_re[4] = {0.f, 0.f, 0.f, 0.f};
    float ws_im[4] = {0.f, 0.f, 0.f, 0.f};
    if (tseg >= d) {
      const int q2 = q - d * (N4PB * 11);    // (tseg-d, same n4l)
      wp_re = lds[q2 + 0]; wp_im = lds[q2 + 1];
#pragma unroll
      for (int j = 0; j < 4; ++j) { ws_re[j] = lds[q2 + 2 + j]; ws_im[j] = lds[q2 + 6 + j]; }
    }
    __syncthreads();
    if (tseg >= d) {
      // combine(earlier = w, later = v): p' = vp*wp ; s' = vp*ws + vs
      const float np_re = vp_re * wp_re - vp_im * wp_im;
      const float np_im = vp_re * wp_im + vp_im * wp_re;
#pragma unroll
      for (int j = 0; j < 4; ++j) {
        const float ns_re = vp_re * ws_re[j] - vp_im * ws_im[j] + vs_re[j];
        const float ns_im = vp_re * ws_im[j] + vp_im * ws_re[j] + vs_im[j];
        vs_re[j] = ns_re; vs_im[j] = ns_im;
      }
      vp_re = np_re; vp_im = np_im;
      lds[q + 0] = vp_re; lds[q + 1] = vp_im;
#pragma unroll
      for (int j = 0; j < 4; ++j) { lds[q + 2 + j] = vs_re[j]; lds[q + 6 + j] = vs_im[j]; }
    }
  }
  __syncthreads();

  // ---- exclusive carry = inclusive value of segment tseg-1 (same n4l) ----
  float y_re[4] = {0.f, 0.f, 0.f, 0.f};
  float y_im[4] = {0.f, 0.f, 0.f, 0.f};
  if (tseg > 0) {
    const int qc = q - N4PB * 11;
#pragma unroll
    for (int j = 0; j < 4; ++j) { y_re[j] = lds[qc + 2 + j]; y_im[j] = lds[qc + 6 + j]; }
  }

  // ---- pass 2: apply carry from registers, store coalesced ----
  const int ob = (b * LL + t0) * (2 * AN) + n4 * 2;  // f32x4 index into out
#pragma unroll
  for (int t = 0; t < TT; ++t) {
    const float are = ar[t], aim = ai[t];
#pragma unroll
    for (int j = 0; j < 4; ++j) {
      const float ny_re = are * y_re[j] - aim * y_im[j] + xr[t][j];
      const float ny_im = are * y_im[j] + aim * y_re[j] + xi[t][j];
      y_re[j] = ny_re; y_im[j] = ny_im;
    }
    f32x4 o0 = {y_re[0], y_im[0], y_re[1], y_im[1]};
    f32x4 o1 = {y_re[2], y_im[2], y_re[3], y_im[3]};
    out4[ob + t * (2 * AN)]     = o0;
    out4[ob + t * (2 * AN) + 1] = o1;
  }
}

extern "C" void kernel_launch(void* const* d_in, const int* in_sizes, int n_in,
                              void* d_out, int out_size, void* d_ws, size_t ws_size,
                              hipStream_t stream) {
  const float* A_re  = (const float*)d_in[0];
  const float* A_im  = (const float*)d_in[1];
  const f32x4* X_re4 = (const f32x4*)d_in[2];
  const f32x4* X_im4 = (const f32x4*)d_in[3];
  f32x4* out4 = (f32x4*)d_out;
  (void)d_ws; (void)ws_size;  // no workspace needed

  const int blocks = BB * (AN / N4PB);   // 256 blocks: one per (b, 4-n4 group)
  pscan_onepass3<<<blocks, TPB, 0, stream>>>(A_re, A_im, X_re4, X_im4, out4);
}